// Round 12
// baseline (106.036 us; speedup 1.0000x reference)
//
#include <hip/hip_runtime.h>

// CTC batch cost (keras ctc_batch_cost semantics), blank = C-1.
// 256 blocks x 128 threads: wave 0 = DP consumer, wave 1 = producer.
// Lane L owns states 4L..4L+3; lane 63 also owns state 256.
// f64 probability-domain DP (no transcendentals in the loop), exact
// power-of-2 rescale every 16 steps via DPP exponent-max reduce.
// Producer: issues global_load_lds into a 4-slot f32 LDS ring, DEPTH-3
// (51 outstanding <= 63), gated by counted s_waitcnt vmcnt(34); then
// converts chunk k+1 f32 -> f64 (+eps) into an f64 LDS ring while its
// newer loads fly; lgkmcnt(0) before s_barrier for cross-wave visibility.
// Consumer: pure f64 DP from the f64 ring (no cvt/eps on the hot path).
// All staging data lives in LDS - no asm register buffers (rounds 7-10
// proved those corrupt execution beyond ~48 in flight).

constexpr int   Tn    = 1024;
constexpr int   Cc    = 128;
constexpr int   Ln    = 128;
constexpr float EPSf  = 1e-7f;
constexpr int   CK    = 8;     // rows per chunk
constexpr int   NSLOT = 4;     // ring slots (3 ahead + 1 being read)

__device__ __forceinline__ int dpp_max_i32(int m) {
    int o;
    o = __builtin_amdgcn_update_dpp(0, m, 0x111, 0xf, 0xf, false); m = o > m ? o : m; // row_shr:1
    o = __builtin_amdgcn_update_dpp(0, m, 0x112, 0xf, 0xf, false); m = o > m ? o : m; // row_shr:2
    o = __builtin_amdgcn_update_dpp(0, m, 0x114, 0xf, 0xf, false); m = o > m ? o : m; // row_shr:4
    o = __builtin_amdgcn_update_dpp(0, m, 0x118, 0xf, 0xf, false); m = o > m ? o : m; // row_shr:8
    o = __builtin_amdgcn_update_dpp(0, m, 0x142, 0xf, 0xf, false); m = o > m ? o : m; // row_bcast:15
    o = __builtin_amdgcn_update_dpp(0, m, 0x143, 0xf, 0xf, false); m = o > m ? o : m; // row_bcast:31
    return m;   // lane 63 holds the wave max
}

// lane L gets lane L-1's value; lane 0 gets exact +0.0 (bound_ctrl=1).
__device__ __forceinline__ double dpp_shr1_f64(double x) {
    const int lo = __double2loint(x), hi = __double2hiint(x);
    const int slo = __builtin_amdgcn_update_dpp(0, lo, 0x138, 0xf, 0xf, true); // wave_shr:1
    const int shi = __builtin_amdgcn_update_dpp(0, hi, 0x138, 0xf, 0xf, true);
    return __hiloint2double(shi, slo);
}

__global__ __launch_bounds__(128, 1)
void ctc_fwd_kernel(const int*   __restrict__ y_true,
                    const float* __restrict__ y_pred,
                    const int*   __restrict__ in_len,
                    const int*   __restrict__ lab_len,
                    float*       __restrict__ out)
{
    const int tid = threadIdx.x;
    const int L   = tid & 63;            // lane within wave
    const int b   = blockIdx.x;
    const int il  = in_len[b];
    const int ll  = lab_len[b];
    const int blank = Cc - 1;

    const int* yb   = y_true + (size_t)b * Ln;
    const int  lab1 = yb[2 * L];                       // label for state 4L+1
    const int  lab2 = yb[2 * L + 1];                   // label for state 4L+3

    const float* base = y_pred + (size_t)b * Tn * Cc;
    const int steps = (il > 0) ? (il - 1) : 0;         // updates run t = 1 .. il-1
    const int nfull = steps / CK;
    const int nch   = (steps + CK - 1) / CK;

    __shared__ float  f32L1[NSLOT][CK][64];
    __shared__ float  f32L2[NSLOT][CK][64];
    __shared__ float  f32BK[NSLOT][CK];
    __shared__ double q64L1[NSLOT][CK][64];
    __shared__ double q64L2[NSLOT][CK][64];
    __shared__ double q64BK[NSLOT][CK];
    __shared__ double sA[258];

#define BARRIER() do {                                                  \
    __builtin_amdgcn_sched_barrier(0);                                  \
    asm volatile("" ::: "memory");                                      \
    __builtin_amdgcn_s_barrier();                                       \
    asm volatile("" ::: "memory");                                      \
    __builtin_amdgcn_sched_barrier(0);                                  \
} while (0)

#define WAIT_VM(n) do {                                                 \
    __builtin_amdgcn_sched_barrier(0);                                  \
    asm volatile("s_waitcnt vmcnt(" #n ")");                            \
    __builtin_amdgcn_sched_barrier(0);                                  \
} while (0)

#define WAIT_LGKM0() do {                                               \
    __builtin_amdgcn_sched_barrier(0);                                  \
    asm volatile("s_waitcnt lgkmcnt(0)");                               \
    __builtin_amdgcn_sched_barrier(0);                                  \
} while (0)

    if (tid >= 64) {
        // ---------------- producer wave ----------------
        // 17 VMEM per chunk: 1 blank (lanes 0..7 cover rows), 8+8 label rows.
#define ISSUE_CHUNK(k) do {                                             \
    const int slot_ = (k) & (NSLOT - 1);                                \
    {                                                                   \
        int tb_ = 1 + (k) * CK + L; if (tb_ > steps) tb_ = steps; if (tb_ < 0) tb_ = 0; \
        const float* g_ = base + (size_t)tb_ * Cc + blank;              \
        if (L < CK)                                                     \
            __builtin_amdgcn_global_load_lds(                           \
                (const __attribute__((address_space(1))) void*)g_,      \
                (__attribute__((address_space(3))) void*)&f32BK[slot_][0], 4, 0, 0); \
    }                                                                   \
    _Pragma("unroll")                                                   \
    for (int r_ = 0; r_ < CK; ++r_) {                                   \
        int t_ = 1 + (k) * CK + r_; if (t_ > steps) t_ = steps; if (t_ < 0) t_ = 0; \
        const float* row_ = base + (size_t)t_ * Cc;                     \
        __builtin_amdgcn_global_load_lds(                               \
            (const __attribute__((address_space(1))) void*)(row_ + lab1), \
            (__attribute__((address_space(3))) void*)&f32L1[slot_][r_][0], 4, 0, 0); \
        __builtin_amdgcn_global_load_lds(                               \
            (const __attribute__((address_space(1))) void*)(row_ + lab2), \
            (__attribute__((address_space(3))) void*)&f32L2[slot_][r_][0], 4, 0, 0); \
    }                                                                   \
} while (0)

// Convert chunk k: f32 ring -> f64 ring with eps pre-added.
#define CONVERT(k) do {                                                 \
    const int slot_ = (k) & (NSLOT - 1);                                \
    _Pragma("unroll")                                                   \
    for (int r_ = 0; r_ < CK; ++r_) {                                   \
        q64L1[slot_][r_][L] = (double)(f32L1[slot_][r_][L] + EPSf);     \
        q64L2[slot_][r_][L] = (double)(f32L2[slot_][r_][L] + EPSf);     \
    }                                                                   \
    if (L < CK) q64BK[slot_][L] = (double)(f32BK[slot_][L] + EPSf);     \
} while (0)

        ISSUE_CHUNK(0);
        ISSUE_CHUNK(1);
        ISSUE_CHUNK(2);            // 51 outstanding
        WAIT_VM(34);               // chunk 0 landed
        CONVERT(0);
        WAIT_LGKM0();
        BARRIER();
        for (int i = 0; i < nch; ++i) {
            if (i + 3 < nch) {
                ISSUE_CHUNK(i + 3);   // <= 51 outstanding
                WAIT_VM(34);          // chunk i+1 landed (in-order)
            } else {
                WAIT_VM(0);           // tail: drain everything
            }
            if (i + 1 < nch) CONVERT(i + 1);
            WAIT_LGKM0();             // ds_writes visible before barrier
            BARRIER();
        }
        return;
#undef ISSUE_CHUNK
#undef CONVERT
    }

    // ---------------- consumer wave (DP) ----------------
    const int  labp = (L > 0) ? yb[2 * L - 1] : -1;
    const double skm1 = ((L > 0) && (lab1 != blank) && (lab1 != labp)) ? 1.0 : 0.0;
    const double skm3 = ((lab2 != blank) && (lab2 != lab1)) ? 1.0 : 0.0;

    double a0 = 0.0, a1v = 0.0, a2v = 0.0, a3v = 0.0, a4v = 0.0;
    if (L == 0) {
        a0  = (double)(base[blank] + EPSf);
        a1v = (ll > 0) ? (double)(base[lab1] + EPSf) : 0.0;
    }
    int shift = 0;

#define DPSTEP(qb_, q1_, q2_) do {                                      \
    const double pa3_ = dpp_shr1_f64(a3v);                              \
    const double n0_ = (a0 + pa3_) * (qb_);                             \
    const double n1_ = fma(skm1, pa3_, a0 + a1v) * (q1_);               \
    const double n2_ = (a2v + a1v) * (qb_);                             \
    const double n3_ = fma(skm3, a1v, a3v + a2v) * (q2_);               \
    const double n4_ = (a4v + a3v) * (qb_);                             \
    a0 = n0_; a1v = n1_; a2v = n2_; a3v = n3_; a4v = n4_;               \
} while (0)

#define RESCALE() do {                                                  \
    double m_ = fmax(fmax(a0, a1v), fmax(a2v, a3v)); m_ = fmax(m_, a4v);\
    int be_ = (__double2hiint(m_) >> 20) & 0x7ff;                       \
    be_ = dpp_max_i32(be_);                                             \
    const int emax_ = __builtin_amdgcn_readlane(be_, 63);               \
    const double sc_ = __hiloint2double((2046 - emax_) << 20, 0);       \
    a0 *= sc_; a1v *= sc_; a2v *= sc_; a3v *= sc_; a4v *= sc_;          \
    shift += emax_ - 1023;                                              \
} while (0)

    BARRIER();                       // matches producer prologue barrier

    for (int i = 0; i < nch; ++i) {
        const int slot = i & (NSLOT - 1);
        if (i < nfull) {
#pragma unroll
            for (int r = 0; r < CK; ++r)
                DPSTEP(q64BK[slot][r], q64L1[slot][r][L], q64L2[slot][r][L]);
        } else {
#pragma unroll
            for (int r = 0; r < CK; ++r) {
                if (1 + i * CK + r <= steps)
                    DPSTEP(q64BK[slot][r], q64L1[slot][r][L], q64L2[slot][r][L]);
            }
        }
        if ((i & 1) || (i == nch - 1)) RESCALE();   // every 16 steps (exact pow-2)
        BARRIER();
    }

    // ---- readout (single wave; DS ops in-order within the wave) ----
    sA[4 * L + 0] = a0;
    sA[4 * L + 1] = a1v;
    sA[4 * L + 2] = a2v;
    sA[4 * L + 3] = a3v;
    if (L == 63) sA[256] = a4v;

    if (L == 0) {
        const int end = 2 * ll;
        const double ae = sA[end];
        int pi = end - 1; if (pi < 0) pi = 0;
        double ap = sA[pi];
        if (ll <= 0) ap = 0.0;
        const double s  = ae + ap;
        const double lg = log2(s) + (double)shift;
        out[b] = (float)(-0.6931471805599453 * lg);
    }

#undef BARRIER
#undef WAIT_VM
#undef WAIT_LGKM0
#undef DPSTEP
#undef RESCALE
}

extern "C" void kernel_launch(void* const* d_in, const int* in_sizes, int n_in,
                              void* d_out, int out_size, void* d_ws, size_t ws_size,
                              hipStream_t stream) {
    const int*   y_true  = (const int*)  d_in[0];
    const float* y_pred  = (const float*)d_in[1];
    const int*   in_len  = (const int*)  d_in[2];
    const int*   lab_len = (const int*)  d_in[3];
    float*       out     = (float*)      d_out;

    ctc_fwd_kernel<<<dim3(256), dim3(128), 0, stream>>>(y_true, y_pred, in_len, lab_len, out);
}

// Round 13
// 58.217 us; speedup vs baseline: 1.8214x; 1.8214x over previous
//
#include <hip/hip_runtime.h>

// CTC batch cost (keras ctc_batch_cost semantics), blank = C-1.
// 256 blocks x 128 threads: wave 0 = DP consumer, wave 1 = producer.
// Lane L owns states 4L..4L+3; lane 63 also owns state 256.
// f64 probability-domain DP (no transcendentals in the loop), exact
// power-of-2 rescale every CK=12 steps via DPP exponent-max reduce.
// Producer: 25 global_load_lds per chunk into a 4-slot f32 LDS ring,
// depth-2 (50 outstanding <= 63), gated by counted s_waitcnt vmcnt(25)
// + raw s_barrier. Consumer: batch-reads + converts the whole chunk to
// f64 registers at chunk top (hides ds_read latency behind back-to-back
// issues), then runs pure-register DP steps.
// r12's producer-side f64 convert REVERTED: it serialized ~34 DS ops +
// lgkmcnt(0) on the producer's barrier path (64->106us regression).
// All staging lives in LDS: rounds 7-10 proved asm register buffers
// corrupt execution beyond ~48 in flight.

constexpr int   Tn    = 1024;
constexpr int   Cc    = 128;
constexpr int   Ln    = 128;
constexpr float EPSf  = 1e-7f;
constexpr int   CK    = 12;    // rows per chunk == rescale period
constexpr int   NSLOT = 4;     // LDS ring slots

__device__ __forceinline__ int dpp_max_i32(int m) {
    int o;
    o = __builtin_amdgcn_update_dpp(0, m, 0x111, 0xf, 0xf, false); m = o > m ? o : m; // row_shr:1
    o = __builtin_amdgcn_update_dpp(0, m, 0x112, 0xf, 0xf, false); m = o > m ? o : m; // row_shr:2
    o = __builtin_amdgcn_update_dpp(0, m, 0x114, 0xf, 0xf, false); m = o > m ? o : m; // row_shr:4
    o = __builtin_amdgcn_update_dpp(0, m, 0x118, 0xf, 0xf, false); m = o > m ? o : m; // row_shr:8
    o = __builtin_amdgcn_update_dpp(0, m, 0x142, 0xf, 0xf, false); m = o > m ? o : m; // row_bcast:15
    o = __builtin_amdgcn_update_dpp(0, m, 0x143, 0xf, 0xf, false); m = o > m ? o : m; // row_bcast:31
    return m;   // lane 63 holds the wave max
}

// lane L gets lane L-1's value; lane 0 gets exact +0.0 (bound_ctrl=1).
__device__ __forceinline__ double dpp_shr1_f64(double x) {
    const int lo = __double2loint(x), hi = __double2hiint(x);
    const int slo = __builtin_amdgcn_update_dpp(0, lo, 0x138, 0xf, 0xf, true); // wave_shr:1
    const int shi = __builtin_amdgcn_update_dpp(0, hi, 0x138, 0xf, 0xf, true);
    return __hiloint2double(shi, slo);
}

__global__ __launch_bounds__(128, 1)
void ctc_fwd_kernel(const int*   __restrict__ y_true,
                    const float* __restrict__ y_pred,
                    const int*   __restrict__ in_len,
                    const int*   __restrict__ lab_len,
                    float*       __restrict__ out)
{
    const int tid = threadIdx.x;
    const int L   = tid & 63;            // lane within wave
    const int b   = blockIdx.x;
    const int il  = in_len[b];
    const int ll  = lab_len[b];
    const int blank = Cc - 1;

    const int* yb   = y_true + (size_t)b * Ln;
    const int  lab1 = yb[2 * L];                       // label for state 4L+1
    const int  lab2 = yb[2 * L + 1];                   // label for state 4L+3

    const float* base = y_pred + (size_t)b * Tn * Cc;
    const int steps = (il > 0) ? (il - 1) : 0;         // updates run t = 1 .. il-1
    const int nfull = steps / CK;
    const int nch   = (steps + CK - 1) / CK;

    __shared__ float  f32L1[NSLOT][CK][64];
    __shared__ float  f32L2[NSLOT][CK][64];
    __shared__ float  f32BK[NSLOT][CK];
    __shared__ double sA[258];

#define BARRIER() do {                                                  \
    __builtin_amdgcn_sched_barrier(0);                                  \
    asm volatile("" ::: "memory");                                      \
    __builtin_amdgcn_s_barrier();                                       \
    asm volatile("" ::: "memory");                                      \
    __builtin_amdgcn_sched_barrier(0);                                  \
} while (0)

#define WAIT_VM(n) do {                                                 \
    __builtin_amdgcn_sched_barrier(0);                                  \
    asm volatile("s_waitcnt vmcnt(" #n ")");                            \
    __builtin_amdgcn_sched_barrier(0);                                  \
} while (0)

    if (tid >= 64) {
        // ---------------- producer wave ----------------
        // 25 VMEM per chunk: 1 blank (lanes 0..11 cover rows), 12+12 label rows.
#define ISSUE_CHUNK(k) do {                                             \
    const int slot_ = (k) & (NSLOT - 1);                                \
    {                                                                   \
        int tb_ = 1 + (k) * CK + L; if (tb_ > steps) tb_ = steps; if (tb_ < 0) tb_ = 0; \
        const float* g_ = base + (size_t)tb_ * Cc + blank;              \
        if (L < CK)                                                     \
            __builtin_amdgcn_global_load_lds(                           \
                (const __attribute__((address_space(1))) void*)g_,      \
                (__attribute__((address_space(3))) void*)&f32BK[slot_][0], 4, 0, 0); \
    }                                                                   \
    _Pragma("unroll")                                                   \
    for (int r_ = 0; r_ < CK; ++r_) {                                   \
        int t_ = 1 + (k) * CK + r_; if (t_ > steps) t_ = steps; if (t_ < 0) t_ = 0; \
        const float* row_ = base + (size_t)t_ * Cc;                     \
        __builtin_amdgcn_global_load_lds(                               \
            (const __attribute__((address_space(1))) void*)(row_ + lab1), \
            (__attribute__((address_space(3))) void*)&f32L1[slot_][r_][0], 4, 0, 0); \
        __builtin_amdgcn_global_load_lds(                               \
            (const __attribute__((address_space(1))) void*)(row_ + lab2), \
            (__attribute__((address_space(3))) void*)&f32L2[slot_][r_][0], 4, 0, 0); \
    }                                                                   \
} while (0)

        ISSUE_CHUNK(0);
        ISSUE_CHUNK(1);              // 50 outstanding
        WAIT_VM(25);                 // chunk 0 landed
        BARRIER();
        for (int i = 0; i < nch; ++i) {
            if (i + 2 < nch) {
                ISSUE_CHUNK(i + 2);  // <= 50 outstanding
                WAIT_VM(25);         // chunk i+1 landed (in-order)
            } else {
                WAIT_VM(0);          // tail: drain everything
            }
            BARRIER();
        }
        return;
#undef ISSUE_CHUNK
    }

    // ---------------- consumer wave (DP) ----------------
    const int  labp = (L > 0) ? yb[2 * L - 1] : -1;
    const double skm1 = ((L > 0) && (lab1 != blank) && (lab1 != labp)) ? 1.0 : 0.0;
    const double skm3 = ((lab2 != blank) && (lab2 != lab1)) ? 1.0 : 0.0;

    double a0 = 0.0, a1v = 0.0, a2v = 0.0, a3v = 0.0, a4v = 0.0;
    if (L == 0) {
        a0  = (double)(base[blank] + EPSf);
        a1v = (ll > 0) ? (double)(base[lab1] + EPSf) : 0.0;
    }
    int shift = 0;

#define DPSTEP(qb_, q1_, q2_) do {                                      \
    const double pa3_ = dpp_shr1_f64(a3v);                              \
    const double n0_ = (a0 + pa3_) * (qb_);                             \
    const double n1_ = fma(skm1, pa3_, a0 + a1v) * (q1_);               \
    const double n2_ = (a2v + a1v) * (qb_);                             \
    const double n3_ = fma(skm3, a1v, a3v + a2v) * (q2_);               \
    const double n4_ = (a4v + a3v) * (qb_);                             \
    a0 = n0_; a1v = n1_; a2v = n2_; a3v = n3_; a4v = n4_;               \
} while (0)

#define RESCALE() do {                                                  \
    double m_ = fmax(fmax(a0, a1v), fmax(a2v, a3v)); m_ = fmax(m_, a4v);\
    int be_ = (__double2hiint(m_) >> 20) & 0x7ff;                       \
    be_ = dpp_max_i32(be_);                                             \
    const int emax_ = __builtin_amdgcn_readlane(be_, 63);               \
    const double sc_ = __hiloint2double((2046 - emax_) << 20, 0);       \
    a0 *= sc_; a1v *= sc_; a2v *= sc_; a3v *= sc_; a4v *= sc_;          \
    shift += emax_ - 1023;                                              \
} while (0)

    BARRIER();                       // matches producer prologue barrier

    for (int i = 0; i < nch; ++i) {
        const int slot = i & (NSLOT - 1);

        // Batch-read + convert the whole chunk into registers (static idx).
        double qb[CK], q1[CK], q2[CK];
#pragma unroll
        for (int r = 0; r < CK; ++r) {
            qb[r] = (double)(f32BK[slot][r]    + EPSf);
            q1[r] = (double)(f32L1[slot][r][L] + EPSf);
            q2[r] = (double)(f32L2[slot][r][L] + EPSf);
        }

        if (i < nfull) {
#pragma unroll
            for (int r = 0; r < CK; ++r)
                DPSTEP(qb[r], q1[r], q2[r]);
        } else {
#pragma unroll
            for (int r = 0; r < CK; ++r) {
                if (1 + i * CK + r <= steps)
                    DPSTEP(qb[r], q1[r], q2[r]);
            }
        }
        RESCALE();                   // every 12 steps (exact pow-2)
        BARRIER();
    }

    // ---- readout (single wave; DS ops in-order within the wave) ----
    sA[4 * L + 0] = a0;
    sA[4 * L + 1] = a1v;
    sA[4 * L + 2] = a2v;
    sA[4 * L + 3] = a3v;
    if (L == 63) sA[256] = a4v;

    if (L == 0) {
        const int end = 2 * ll;
        const double ae = sA[end];
        int pi = end - 1; if (pi < 0) pi = 0;
        double ap = sA[pi];
        if (ll <= 0) ap = 0.0;
        const double s  = ae + ap;
        const double lg = log2(s) + (double)shift;
        out[b] = (float)(-0.6931471805599453 * lg);
    }

#undef BARRIER
#undef WAIT_VM
#undef DPSTEP
#undef RESCALE
}

extern "C" void kernel_launch(void* const* d_in, const int* in_sizes, int n_in,
                              void* d_out, int out_size, void* d_ws, size_t ws_size,
                              hipStream_t stream) {
    const int*   y_true  = (const int*)  d_in[0];
    const float* y_pred  = (const float*)d_in[1];
    const int*   in_len  = (const int*)  d_in[2];
    const int*   lab_len = (const int*)  d_in[3];
    float*       out     = (float*)      d_out;

    ctc_fwd_kernel<<<dim3(256), dim3(128), 0, stream>>>(y_true, y_pred, in_len, lab_len, out);
}